// Round 1
// baseline (234.243 us; speedup 1.0000x reference)
//
#include <hip/hip_runtime.h>
#include <math.h>

// Problem constants
constexpr int Bn   = 32;
constexpr int Cn   = 256;
constexpr int Kn   = 4;
constexpr int HIDn = 32;
constexpr int HWn  = 56 * 56;        // 3136
constexpr int HW4n = HWn / 4;        // 784 float4 per plane
constexpr int CK1  = Cn * (Kn + 1);  // 1280

// ---------------------------------------------------------------------------
// Kernel 1: global average pool.
// blockIdx.x = (k*B + b)*C + c, k=0 -> y, k=1..K -> x[k-1].
// Writes mean into w_in[b*CK1 + k*C + c] (the concat+transpose layout).
// ---------------------------------------------------------------------------
__global__ __launch_bounds__(256) void pool_kernel(const float* __restrict__ y,
                                                   const float* __restrict__ x,
                                                   float* __restrict__ w_in) {
    int bid = blockIdx.x;
    int c = bid % Cn;
    int kb = bid / Cn;
    int b = kb % Bn;
    int k = kb / Bn;

    const float* src = (k == 0)
        ? (y + (size_t)(b * Cn + c) * HWn)
        : (x + ((size_t)((k - 1) * Bn + b) * Cn + c) * HWn);
    const float4* src4 = reinterpret_cast<const float4*>(src);

    float s = 0.f;
    for (int i = threadIdx.x; i < HW4n; i += 256) {
        float4 v = src4[i];
        s += (v.x + v.y) + (v.z + v.w);
    }
    // wave (64-lane) shuffle reduce
    #pragma unroll
    for (int off = 32; off > 0; off >>= 1) s += __shfl_down(s, off, 64);

    __shared__ float part[4];
    int lane = threadIdx.x & 63;
    int wid  = threadIdx.x >> 6;
    if (lane == 0) part[wid] = s;
    __syncthreads();
    if (threadIdx.x == 0) {
        float t = (part[0] + part[1]) + (part[2] + part[3]);
        w_in[b * CK1 + k * Cn + c] = t * (1.0f / (float)HWn);
    }
}

// ---------------------------------------------------------------------------
// Kernel 2: tiny MLP + gates. One block per batch (32 blocks x 256 threads).
// h = relu((w_in @ W1^T) * gamma + beta)   [HID]
// w = h @ W2^T + b2                        [CK1]
// gates[b][0][c]   = sigmoid(w[c])
// gates[b][k][c]   = softmax over k of w[k*C+c], k=1..K
// ---------------------------------------------------------------------------
__global__ __launch_bounds__(256) void mlp_kernel(const float* __restrict__ w_in,
                                                  const float* __restrict__ W1,
                                                  const float* __restrict__ gamma,
                                                  const float* __restrict__ beta,
                                                  const float* __restrict__ W2,
                                                  const float* __restrict__ b2,
                                                  float* __restrict__ gates) {
    int b = blockIdx.x;
    __shared__ float s_in[CK1];
    __shared__ float s_h[HIDn];
    __shared__ float s_w[CK1];

    for (int i = threadIdx.x; i < CK1; i += 256) s_in[i] = w_in[b * CK1 + i];
    __syncthreads();

    // h: 8 threads per output j (32 j's x 8 = 256 threads)
    {
        int j   = threadIdx.x >> 3;  // 0..31
        int sub = threadIdx.x & 7;
        const float* w1row = W1 + j * CK1;
        float p = 0.f;
        for (int i = sub; i < CK1; i += 8) p += s_in[i] * w1row[i];
        p += __shfl_xor(p, 1);
        p += __shfl_xor(p, 2);
        p += __shfl_xor(p, 4);
        if (sub == 0) {
            float hv = p * gamma[j] + beta[j];
            s_h[j] = hv > 0.f ? hv : 0.f;
        }
    }
    __syncthreads();

    // w = h @ W2^T + b2
    for (int o = threadIdx.x; o < CK1; o += 256) {
        const float* w2row = W2 + o * HIDn;
        float acc = b2[o];
        #pragma unroll
        for (int i = 0; i < HIDn; ++i) acc += s_h[i] * w2row[i];
        s_w[o] = acc;
    }
    __syncthreads();

    // gates (one thread per channel c)
    int c = threadIdx.x;  // 256 threads == C
    float g0 = 1.f / (1.f + expf(-s_w[c]));
    float s1 = s_w[Cn + c], s2 = s_w[2 * Cn + c], s3 = s_w[3 * Cn + c], s4 = s_w[4 * Cn + c];
    float m  = fmaxf(fmaxf(s1, s2), fmaxf(s3, s4));
    float e1 = expf(s1 - m), e2 = expf(s2 - m), e3 = expf(s3 - m), e4 = expf(s4 - m);
    float inv = 1.f / (e1 + e2 + e3 + e4);
    float* g = gates + (size_t)b * (5 * Cn);
    g[c]          = g0;
    g[Cn + c]     = e1 * inv;
    g[2 * Cn + c] = e2 * inv;
    g[3 * Cn + c] = e3 * inv;
    g[4 * Cn + c] = e4 * inv;
}

// ---------------------------------------------------------------------------
// Kernel 3: apply gates. One block per (b,c) plane, float4 fused weighted sum.
// out = y*g0 + sum_k gk * x[k]
// ---------------------------------------------------------------------------
__global__ __launch_bounds__(256) void apply_kernel(const float* __restrict__ y,
                                                    const float* __restrict__ x,
                                                    const float* __restrict__ gates,
                                                    float* __restrict__ out) {
    int bid = blockIdx.x;     // b*C + c
    int c = bid % Cn;
    int b = bid / Cn;
    const float* g = gates + (size_t)b * (5 * Cn);
    float g0 = g[c];
    float g1 = g[Cn + c];
    float g2 = g[2 * Cn + c];
    float g3 = g[3 * Cn + c];
    float g4 = g[4 * Cn + c];

    size_t plane = (size_t)bid * HWn;
    size_t xstep = (size_t)Bn * Cn * HWn;
    const float4* y4  = reinterpret_cast<const float4*>(y + plane);
    const float4* x14 = reinterpret_cast<const float4*>(x + plane);
    const float4* x24 = reinterpret_cast<const float4*>(x + plane + xstep);
    const float4* x34 = reinterpret_cast<const float4*>(x + plane + 2 * xstep);
    const float4* x44 = reinterpret_cast<const float4*>(x + plane + 3 * xstep);
    float4* o4 = reinterpret_cast<float4*>(out + plane);

    for (int i = threadIdx.x; i < HW4n; i += 256) {
        float4 vy = y4[i];
        float4 v1 = x14[i];
        float4 v2 = x24[i];
        float4 v3 = x34[i];
        float4 v4 = x44[i];
        float4 r;
        r.x = vy.x * g0 + v1.x * g1 + v2.x * g2 + v3.x * g3 + v4.x * g4;
        r.y = vy.y * g0 + v1.y * g1 + v2.y * g2 + v3.y * g3 + v4.y * g4;
        r.z = vy.z * g0 + v1.z * g1 + v2.z * g2 + v3.z * g3 + v4.z * g4;
        r.w = vy.w * g0 + v1.w * g1 + v2.w * g2 + v3.w * g3 + v4.w * g4;
        o4[i] = r;
    }
}

extern "C" void kernel_launch(void* const* d_in, const int* in_sizes, int n_in,
                              void* d_out, int out_size, void* d_ws, size_t ws_size,
                              hipStream_t stream) {
    const float* y     = (const float*)d_in[0];
    const float* x     = (const float*)d_in[1];
    const float* W1    = (const float*)d_in[2];
    const float* gamma = (const float*)d_in[3];
    const float* beta  = (const float*)d_in[4];
    const float* W2    = (const float*)d_in[5];
    const float* b2    = (const float*)d_in[6];
    float* out = (float*)d_out;

    float* w_in  = (float*)d_ws;                       // [B, CK1]
    float* gates = w_in + (size_t)Bn * CK1;            // [B, 5, C]

    pool_kernel<<<(Kn + 1) * Bn * Cn, 256, 0, stream>>>(y, x, w_in);
    mlp_kernel<<<Bn, 256, 0, stream>>>(w_in, W1, gamma, beta, W2, b2, gates);
    apply_kernel<<<Bn * Cn, 256, 0, stream>>>(y, x, gates, out);
}

// Round 3
// 198.182 us; speedup vs baseline: 1.1820x; 1.1820x over previous
//
#include <hip/hip_runtime.h>
#include <math.h>

// Native clang vector type (works with __builtin_nontemporal_*)
typedef float f4 __attribute__((ext_vector_type(4)));

// Problem constants
constexpr int Bn   = 32;
constexpr int Cn   = 256;
constexpr int Kn   = 4;
constexpr int HIDn = 32;
constexpr int HWn  = 56 * 56;        // 3136
constexpr int HW4n = HWn / 4;        // 784 f4 per plane
constexpr int CK1  = Cn * (Kn + 1);  // 1280
constexpr int ROWS = (Kn + 1) * Bn * Cn;  // 40960 pool rows

// ---------------------------------------------------------------------------
// Kernel 1: global average pool. ONE WAVE per (k,b,c) row — no LDS, no
// __syncthreads. k=0 -> y, k=1..K -> x[k-1]. x reads are nontemporal so the
// L3 keeps y resident for the apply pass.
// ---------------------------------------------------------------------------
__global__ __launch_bounds__(256) void pool_kernel(const float* __restrict__ y,
                                                   const float* __restrict__ x,
                                                   float* __restrict__ w_in) {
    int row  = blockIdx.x * 4 + (threadIdx.x >> 6);   // global wave id = row
    int lane = threadIdx.x & 63;
    if (row >= ROWS) return;

    int c  = row % Cn;
    int kb = row / Cn;
    int b  = kb % Bn;
    int k  = kb / Bn;

    float s = 0.f;
    if (k == 0) {
        const f4* s4 = reinterpret_cast<const f4*>(y + (size_t)(b * Cn + c) * HWn);
        for (int i = lane; i < HW4n; i += 64) {
            f4 v = s4[i];
            s += (v.x + v.y) + (v.z + v.w);
        }
    } else {
        const f4* s4 = reinterpret_cast<const f4*>(
            x + ((size_t)((k - 1) * Bn + b) * Cn + c) * HWn);
        for (int i = lane; i < HW4n; i += 64) {
            f4 v = __builtin_nontemporal_load(s4 + i);
            s += (v.x + v.y) + (v.z + v.w);
        }
    }

    // 64-lane butterfly reduce
    #pragma unroll
    for (int off = 32; off > 0; off >>= 1) s += __shfl_xor(s, off, 64);

    if (lane == 0) w_in[b * CK1 + k * Cn + c] = s * (1.0f / (float)HWn);
}

// ---------------------------------------------------------------------------
// Kernel 2: tiny MLP + gates. One block per batch (32 blocks x 256 threads).
// ---------------------------------------------------------------------------
__global__ __launch_bounds__(256) void mlp_kernel(const float* __restrict__ w_in,
                                                  const float* __restrict__ W1,
                                                  const float* __restrict__ gamma,
                                                  const float* __restrict__ beta,
                                                  const float* __restrict__ W2,
                                                  const float* __restrict__ b2,
                                                  float* __restrict__ gates) {
    int b = blockIdx.x;
    __shared__ float s_in[CK1];
    __shared__ float s_h[HIDn];
    __shared__ float s_w[CK1];

    for (int i = threadIdx.x; i < CK1; i += 256) s_in[i] = w_in[b * CK1 + i];
    __syncthreads();

    // h: 8 threads per output j (32 j's x 8 = 256 threads)
    {
        int j   = threadIdx.x >> 3;  // 0..31
        int sub = threadIdx.x & 7;
        const float* w1row = W1 + j * CK1;
        float p = 0.f;
        for (int i = sub; i < CK1; i += 8) p += s_in[i] * w1row[i];
        p += __shfl_xor(p, 1);
        p += __shfl_xor(p, 2);
        p += __shfl_xor(p, 4);
        if (sub == 0) {
            float hv = p * gamma[j] + beta[j];
            s_h[j] = hv > 0.f ? hv : 0.f;
        }
    }
    __syncthreads();

    // w = h @ W2^T + b2
    for (int o = threadIdx.x; o < CK1; o += 256) {
        const float* w2row = W2 + o * HIDn;
        float acc = b2[o];
        #pragma unroll
        for (int i = 0; i < HIDn; ++i) acc += s_h[i] * w2row[i];
        s_w[o] = acc;
    }
    __syncthreads();

    // gates (one thread per channel c)
    int c = threadIdx.x;  // 256 threads == C
    float g0 = 1.f / (1.f + expf(-s_w[c]));
    float s1 = s_w[Cn + c], s2 = s_w[2 * Cn + c], s3 = s_w[3 * Cn + c], s4 = s_w[4 * Cn + c];
    float m  = fmaxf(fmaxf(s1, s2), fmaxf(s3, s4));
    float e1 = expf(s1 - m), e2 = expf(s2 - m), e3 = expf(s3 - m), e4 = expf(s4 - m);
    float inv = 1.f / (e1 + e2 + e3 + e4);
    float* g = gates + (size_t)b * (5 * Cn);
    g[c]          = g0;
    g[Cn + c]     = e1 * inv;
    g[2 * Cn + c] = e2 * inv;
    g[3 * Cn + c] = e3 * inv;
    g[4 * Cn + c] = e4 * inv;
}

// ---------------------------------------------------------------------------
// Kernel 3: apply gates. One block per (b,c) plane, f4 fused weighted sum.
// x loads nontemporal (streamed once, no reuse); y load cached (hits L3 from
// pool pass); out store nontemporal (written once).
// ---------------------------------------------------------------------------
__global__ __launch_bounds__(256) void apply_kernel(const float* __restrict__ y,
                                                    const float* __restrict__ x,
                                                    const float* __restrict__ gates,
                                                    float* __restrict__ out) {
    int bid = blockIdx.x;     // b*C + c
    int c = bid % Cn;
    int b = bid / Cn;
    const float* g = gates + (size_t)b * (5 * Cn);
    float g0 = g[c];
    float g1 = g[Cn + c];
    float g2 = g[2 * Cn + c];
    float g3 = g[3 * Cn + c];
    float g4 = g[4 * Cn + c];

    size_t plane = (size_t)bid * HWn;
    size_t xstep = (size_t)Bn * Cn * HWn;
    const f4* y4  = reinterpret_cast<const f4*>(y + plane);
    const f4* x14 = reinterpret_cast<const f4*>(x + plane);
    const f4* x24 = reinterpret_cast<const f4*>(x + plane + xstep);
    const f4* x34 = reinterpret_cast<const f4*>(x + plane + 2 * xstep);
    const f4* x44 = reinterpret_cast<const f4*>(x + plane + 3 * xstep);
    f4* o4 = reinterpret_cast<f4*>(out + plane);

    for (int i = threadIdx.x; i < HW4n; i += 256) {
        f4 vy = y4[i];
        f4 v1 = __builtin_nontemporal_load(x14 + i);
        f4 v2 = __builtin_nontemporal_load(x24 + i);
        f4 v3 = __builtin_nontemporal_load(x34 + i);
        f4 v4 = __builtin_nontemporal_load(x44 + i);
        f4 r;
        r.x = vy.x * g0 + v1.x * g1 + v2.x * g2 + v3.x * g3 + v4.x * g4;
        r.y = vy.y * g0 + v1.y * g1 + v2.y * g2 + v3.y * g3 + v4.y * g4;
        r.z = vy.z * g0 + v1.z * g1 + v2.z * g2 + v3.z * g3 + v4.z * g4;
        r.w = vy.w * g0 + v1.w * g1 + v2.w * g2 + v3.w * g3 + v4.w * g4;
        __builtin_nontemporal_store(r, o4 + i);
    }
}

extern "C" void kernel_launch(void* const* d_in, const int* in_sizes, int n_in,
                              void* d_out, int out_size, void* d_ws, size_t ws_size,
                              hipStream_t stream) {
    const float* y     = (const float*)d_in[0];
    const float* x     = (const float*)d_in[1];
    const float* W1    = (const float*)d_in[2];
    const float* gamma = (const float*)d_in[3];
    const float* beta  = (const float*)d_in[4];
    const float* W2    = (const float*)d_in[5];
    const float* b2    = (const float*)d_in[6];
    float* out = (float*)d_out;

    float* w_in  = (float*)d_ws;                       // [B, CK1]
    float* gates = w_in + (size_t)Bn * CK1;            // [B, 5, C]

    pool_kernel<<<ROWS / 4, 256, 0, stream>>>(y, x, w_in);
    mlp_kernel<<<Bn, 256, 0, stream>>>(w_in, W1, gamma, beta, W2, b2, gates);
    apply_kernel<<<Bn * Cn, 256, 0, stream>>>(y, x, gates, out);
}

// Round 4
// 192.713 us; speedup vs baseline: 1.2155x; 1.0284x over previous
//
#include <hip/hip_runtime.h>
#include <math.h>

// Native clang vector type (works with __builtin_nontemporal_*)
typedef float f4 __attribute__((ext_vector_type(4)));

// Problem constants
constexpr int Bn   = 32;
constexpr int Cn   = 256;
constexpr int Kn   = 4;
constexpr int HIDn = 32;
constexpr int HWn  = 56 * 56;        // 3136
constexpr int HW4n = HWn / 4;        // 784 f4 per plane
constexpr int CK1  = Cn * (Kn + 1);  // 1280
constexpr int ROWS = (Kn + 1) * Bn * Cn;  // 40960 pool rows

// ---------------------------------------------------------------------------
// Kernel 1: global average pool. ONE WAVE per (k,b,c) row.
// L3 tiering: y (k=0) and x-branch-0 (k=1) use CACHED loads so they stay
// resident in the 256MB Infinity Cache for the apply pass (206 MB total);
// x branches 1-3 (k=2..4) are nontemporal (streamed, no-allocate).
// ---------------------------------------------------------------------------
__global__ __launch_bounds__(256) void pool_kernel(const float* __restrict__ y,
                                                   const float* __restrict__ x,
                                                   float* __restrict__ w_in) {
    int row  = blockIdx.x * 4 + (threadIdx.x >> 6);   // global wave id = row
    int lane = threadIdx.x & 63;
    if (row >= ROWS) return;

    int c  = row % Cn;
    int kb = row / Cn;
    int b  = kb % Bn;
    int k  = kb / Bn;

    float s = 0.f;
    if (k <= 1) {  // cached tier: y or x-branch-0
        const float* src = (k == 0)
            ? (y + (size_t)(b * Cn + c) * HWn)
            : (x + (size_t)(b * Cn + c) * HWn);
        const f4* s4 = reinterpret_cast<const f4*>(src);
        for (int i = lane; i < HW4n; i += 64) {
            f4 v = s4[i];
            s += (v.x + v.y) + (v.z + v.w);
        }
    } else {       // streaming tier: x branches 1-3, nontemporal
        const f4* s4 = reinterpret_cast<const f4*>(
            x + ((size_t)((k - 1) * Bn + b) * Cn + c) * HWn);
        for (int i = lane; i < HW4n; i += 64) {
            f4 v = __builtin_nontemporal_load(s4 + i);
            s += (v.x + v.y) + (v.z + v.w);
        }
    }

    // 64-lane butterfly reduce
    #pragma unroll
    for (int off = 32; off > 0; off >>= 1) s += __shfl_xor(s, off, 64);

    if (lane == 0) w_in[b * CK1 + k * Cn + c] = s * (1.0f / (float)HWn);
}

// ---------------------------------------------------------------------------
// Kernel 2: tiny MLP + gates. One block per batch (32 blocks x 256 threads).
// ---------------------------------------------------------------------------
__global__ __launch_bounds__(256) void mlp_kernel(const float* __restrict__ w_in,
                                                  const float* __restrict__ W1,
                                                  const float* __restrict__ gamma,
                                                  const float* __restrict__ beta,
                                                  const float* __restrict__ W2,
                                                  const float* __restrict__ b2,
                                                  float* __restrict__ gates) {
    int b = blockIdx.x;
    __shared__ float s_in[CK1];
    __shared__ float s_h[HIDn];
    __shared__ float s_w[CK1];

    for (int i = threadIdx.x; i < CK1; i += 256) s_in[i] = w_in[b * CK1 + i];
    __syncthreads();

    // h: 8 threads per output j (32 j's x 8 = 256 threads)
    {
        int j   = threadIdx.x >> 3;  // 0..31
        int sub = threadIdx.x & 7;
        const float* w1row = W1 + j * CK1;
        float p = 0.f;
        for (int i = sub; i < CK1; i += 8) p += s_in[i] * w1row[i];
        p += __shfl_xor(p, 1);
        p += __shfl_xor(p, 2);
        p += __shfl_xor(p, 4);
        if (sub == 0) {
            float hv = p * gamma[j] + beta[j];
            s_h[j] = hv > 0.f ? hv : 0.f;
        }
    }
    __syncthreads();

    // w = h @ W2^T + b2
    for (int o = threadIdx.x; o < CK1; o += 256) {
        const float* w2row = W2 + o * HIDn;
        float acc = b2[o];
        #pragma unroll
        for (int i = 0; i < HIDn; ++i) acc += s_h[i] * w2row[i];
        s_w[o] = acc;
    }
    __syncthreads();

    // gates (one thread per channel c)
    int c = threadIdx.x;  // 256 threads == C
    float g0 = 1.f / (1.f + expf(-s_w[c]));
    float s1 = s_w[Cn + c], s2 = s_w[2 * Cn + c], s3 = s_w[3 * Cn + c], s4 = s_w[4 * Cn + c];
    float m  = fmaxf(fmaxf(s1, s2), fmaxf(s3, s4));
    float e1 = expf(s1 - m), e2 = expf(s2 - m), e3 = expf(s3 - m), e4 = expf(s4 - m);
    float inv = 1.f / (e1 + e2 + e3 + e4);
    float* g = gates + (size_t)b * (5 * Cn);
    g[c]          = g0;
    g[Cn + c]     = e1 * inv;
    g[2 * Cn + c] = e2 * inv;
    g[3 * Cn + c] = e3 * inv;
    g[4 * Cn + c] = e4 * inv;
}

// ---------------------------------------------------------------------------
// Kernel 3: apply gates. One block per (b,c) plane, f4 fused weighted sum.
// y and x-branch-0 cached (L3 hits from pool pass); x branches 1-3 NT;
// out store NT (written once, keep it out of L3).
// ---------------------------------------------------------------------------
__global__ __launch_bounds__(256) void apply_kernel(const float* __restrict__ y,
                                                    const float* __restrict__ x,
                                                    const float* __restrict__ gates,
                                                    float* __restrict__ out) {
    int bid = blockIdx.x;     // b*C + c
    int c = bid % Cn;
    int b = bid / Cn;
    const float* g = gates + (size_t)b * (5 * Cn);
    float g0 = g[c];
    float g1 = g[Cn + c];
    float g2 = g[2 * Cn + c];
    float g3 = g[3 * Cn + c];
    float g4 = g[4 * Cn + c];

    size_t plane = (size_t)bid * HWn;
    size_t xstep = (size_t)Bn * Cn * HWn;
    const f4* y4  = reinterpret_cast<const f4*>(y + plane);
    const f4* x14 = reinterpret_cast<const f4*>(x + plane);
    const f4* x24 = reinterpret_cast<const f4*>(x + plane + xstep);
    const f4* x34 = reinterpret_cast<const f4*>(x + plane + 2 * xstep);
    const f4* x44 = reinterpret_cast<const f4*>(x + plane + 3 * xstep);
    f4* o4 = reinterpret_cast<f4*>(out + plane);

    for (int i = threadIdx.x; i < HW4n; i += 256) {
        f4 vy = y4[i];                                    // cached (L3 hit)
        f4 v1 = x14[i];                                   // cached (L3 hit)
        f4 v2 = __builtin_nontemporal_load(x24 + i);
        f4 v3 = __builtin_nontemporal_load(x34 + i);
        f4 v4 = __builtin_nontemporal_load(x44 + i);
        f4 r;
        r.x = vy.x * g0 + v1.x * g1 + v2.x * g2 + v3.x * g3 + v4.x * g4;
        r.y = vy.y * g0 + v1.y * g1 + v2.y * g2 + v3.y * g3 + v4.y * g4;
        r.z = vy.z * g0 + v1.z * g1 + v2.z * g2 + v3.z * g3 + v4.z * g4;
        r.w = vy.w * g0 + v1.w * g1 + v2.w * g2 + v3.w * g3 + v4.w * g4;
        __builtin_nontemporal_store(r, o4 + i);
    }
}

extern "C" void kernel_launch(void* const* d_in, const int* in_sizes, int n_in,
                              void* d_out, int out_size, void* d_ws, size_t ws_size,
                              hipStream_t stream) {
    const float* y     = (const float*)d_in[0];
    const float* x     = (const float*)d_in[1];
    const float* W1    = (const float*)d_in[2];
    const float* gamma = (const float*)d_in[3];
    const float* beta  = (const float*)d_in[4];
    const float* W2    = (const float*)d_in[5];
    const float* b2    = (const float*)d_in[6];
    float* out = (float*)d_out;

    float* w_in  = (float*)d_ws;                       // [B, CK1]
    float* gates = w_in + (size_t)Bn * CK1;            // [B, 5, C]

    pool_kernel<<<ROWS / 4, 256, 0, stream>>>(y, x, w_in);
    mlp_kernel<<<Bn, 256, 0, stream>>>(w_in, W1, gamma, beta, W2, b2, gates);
    apply_kernel<<<Bn * Cn, 256, 0, stream>>>(y, x, gates, out);
}